// Round 3
// baseline (95.283 us; speedup 1.0000x reference)
//
#include <hip/hip_runtime.h>

#define TSD 512      // TS (feature dim)
#define SRC 256
#define TGT 256
#define NB  4        // batch
#define KSCALE 2.885390081777927f   // 2*log2(e): exp2(K*x) == exp(2x)

// ---------------------------------------------------------------------------
// Projection GEMM: 64x64 tiles, 16x16 threads, 4x4 micro-tile, BK=16.
// z=0: hp'[r][o]    = K * (hid . Wh)[r][o]                 (row-major [r][o])
// z=1: epT[b][o][s] = K * ((enc . We)[r][o] + bias[o])     (TRANSPOSED [o][s])
// ---------------------------------------------------------------------------
__global__ __launch_bounds__(256) void proj_kernel(
    const float* __restrict__ hid, const float* __restrict__ enc,
    const float* __restrict__ W, const float* __restrict__ bias,
    float* __restrict__ hp, float* __restrict__ epT)
{
    const int z = blockIdx.z;
    const float* __restrict__ X = z ? enc : hid;
    const int wofs = z ? TSD : 0;

    __shared__ float Xs[16][68];   // [k][m]
    __shared__ float Ws[16][68];   // [k][n]

    const int tx = threadIdx.x, ty = threadIdx.y;
    const int tid = ty * 16 + tx;
    const int o0 = blockIdx.x * 64;
    const int r0 = blockIdx.y * 64;

    const int m  = tid >> 2;        // 0..63
    const int kq = (tid & 3) * 4;   // 0,4,8,12

    float acc[4][4] = {};

    for (int k0 = 0; k0 < TSD; k0 += 16) {
        __syncthreads();
        float4 av = *reinterpret_cast<const float4*>(&X[(r0 + m) * TSD + k0 + kq]);
        float4 wv = *reinterpret_cast<const float4*>(&W[(o0 + m) * (2 * TSD) + wofs + k0 + kq]);
        Xs[kq + 0][m] = av.x; Xs[kq + 1][m] = av.y; Xs[kq + 2][m] = av.z; Xs[kq + 3][m] = av.w;
        Ws[kq + 0][m] = wv.x; Ws[kq + 1][m] = wv.y; Ws[kq + 2][m] = wv.z; Ws[kq + 3][m] = wv.w;
        __syncthreads();
        #pragma unroll
        for (int k = 0; k < 16; ++k) {
            float4 a  = *reinterpret_cast<const float4*>(&Xs[k][ty * 4]);
            float4 bb = *reinterpret_cast<const float4*>(&Ws[k][tx * 4]);
            float ar[4] = {a.x, a.y, a.z, a.w};
            float br[4] = {bb.x, bb.y, bb.z, bb.w};
            #pragma unroll
            for (int i = 0; i < 4; ++i)
                #pragma unroll
                for (int j = 0; j < 4; ++j)
                    acc[i][j] = fmaf(ar[i], br[j], acc[i][j]);
        }
    }

    if (z) {
        const int bb_ = r0 >> 8;              // batch of this row-tile
        const int sl  = (r0 & 255) + ty * 4;  // s within batch
        #pragma unroll
        for (int j = 0; j < 4; ++j) {
            const int o = o0 + tx * 4 + j;
            const float bj = bias[o];
            float4 val;
            val.x = (acc[0][j] + bj) * KSCALE;
            val.y = (acc[1][j] + bj) * KSCALE;
            val.z = (acc[2][j] + bj) * KSCALE;
            val.w = (acc[3][j] + bj) * KSCALE;
            *reinterpret_cast<float4*>(&epT[((size_t)bb_ * TSD + o) * SRC + sl]) = val;
        }
    } else {
        #pragma unroll
        for (int i = 0; i < 4; ++i) {
            const int r = r0 + ty * 4 + i;
            float4 o4;
            o4.x = acc[i][0] * KSCALE; o4.y = acc[i][1] * KSCALE;
            o4.z = acc[i][2] * KSCALE; o4.w = acc[i][3] * KSCALE;
            *reinterpret_cast<float4*>(&hp[r * TSD + o0 + tx * 4]) = o4;
        }
    }
}

// ---------------------------------------------------------------------------
// wave + group reductions (group = 8 contiguous waves = 512 threads sharing t)
// ---------------------------------------------------------------------------
__device__ __forceinline__ float wave_red_sum(float v) {
    #pragma unroll
    for (int off = 1; off < 64; off <<= 1) v += __shfl_xor(v, off, 64);
    return v;
}
__device__ __forceinline__ float wave_red_max(float v) {
    #pragma unroll
    for (int off = 1; off < 64; off <<= 1) v = fmaxf(v, __shfl_xor(v, off, 64));
    return v;
}
// all 1024 threads must call (uniform barriers); result = reduction over the
// 512-thread group containing tid (groups: waves 0-7, waves 8-15)
__device__ __forceinline__ float grp_sum(float val, float (*red)[8], int t, int tid) {
    float w = wave_red_sum(val);
    __syncthreads();
    if ((tid & 63) == 0) red[t][(tid >> 6) & 7] = w;
    __syncthreads();
    float r = 0.f;
    #pragma unroll
    for (int i = 0; i < 8; ++i) r += red[t][i];
    return r;
}
__device__ __forceinline__ float grp_max(float val, float (*red)[8], int t, int tid) {
    float w = wave_red_max(val);
    __syncthreads();
    if ((tid & 63) == 0) red[t][(tid >> 6) & 7] = w;
    __syncthreads();
    float r = red[t][0];
    #pragma unroll
    for (int i = 1; i < 8; ++i) r = fmaxf(r, red[t][i]);
    return r;
}

// ---------------------------------------------------------------------------
// Fused score + softmax + context.
// Block = 1024 threads = (t in 0..1) x (oh in 0..1) x (s in 0..255).
// score[t][s] = sumv - 2 * sum_o v[o] / (exp2(hp'[t][o] + epT[o][s]) + 1)
// ---------------------------------------------------------------------------
__global__ __launch_bounds__(1024, 8) void attn_kernel(
    const float* __restrict__ hp, const float* __restrict__ epT,
    const float* __restrict__ enc, const int* __restrict__ mask,
    const float* __restrict__ v,
    float* __restrict__ ctx_out, float* __restrict__ probs_out)
{
    __shared__ float accs[2][2][SRC];   // [t][oh][s]
    __shared__ float p_lds[2][SRC];
    __shared__ float redv[16];
    __shared__ float red2[2][8];

    const int tid = threadIdx.x;
    const int t  = __builtin_amdgcn_readfirstlane(tid >> 9);        // wave-uniform
    const int oh = __builtin_amdgcn_readfirstlane((tid >> 8) & 1);  // wave-uniform
    const int s  = tid & 255;
    const int b  = blockIdx.y;
    const int tg = blockIdx.x * 2 + t;

    // sum(v): threads 0..511 contribute one element each
    {
        float svp = (tid < TSD) ? v[tid] : 0.f;
        float w = wave_red_sum(svp);
        if ((tid & 63) == 0) redv[tid >> 6] = w;
    }
    __syncthreads();
    float sumv = 0.f;
    #pragma unroll
    for (int i = 0; i < 16; ++i) sumv += redv[i];

    const float* __restrict__ hprow = hp + ((size_t)(b * TGT + tg)) * TSD;  // SGPR base
    const float* __restrict__ epb   = epT + (size_t)b * TSD * SRC + (size_t)oh * 256 * SRC;
    const float* __restrict__ hpo   = hprow + oh * 256;
    const float* __restrict__ vo    = v + oh * 256;

    float acc = 0.f;
    #pragma unroll 4
    for (int oi = 0; oi < 256; ++oi) {
        const float e = epb[oi * SRC + s];                 // coalesced, L2-hot
        const float x = hpo[oi] + e;                       // hpo[oi], vo[oi]: s_load
        const float z = __builtin_amdgcn_exp2f(x);         // = exp(2*(h+e+b))
        acc = fmaf(vo[oi], __builtin_amdgcn_rcpf(z + 1.f), acc);
    }
    accs[t][oh][s] = acc;
    __syncthreads();

    const float score = sumv - 2.f * (accs[t][0][s] + accs[t][1][s]);

    // softmax (values duplicated across oh halves -> sums are 2x, halve them)
    const float bmax = grp_max(score, red2, t, tid);
    const float eE = __expf(score - bmax);
    const float sE = grp_sum(eE, red2, t, tid) * 0.5f;
    const float q = eE / sE;
    const float mq = q * (float)mask[b * SRC + s];
    const float smq = grp_sum(mq, red2, t, tid) * 0.5f;
    const float p = mq / (smq + 1e-12f);
    p_lds[t][s] = p;
    if (oh == 0)
        probs_out[((size_t)(b * TGT + tg)) * SRC + s] = p;
    __syncthreads();

    // context: each t-group's 512 threads own one d column each
    const int d = tid & 511;
    const float* __restrict__ encb = enc + (size_t)b * SRC * TSD;
    float c = 0.f;
    #pragma unroll 4
    for (int s2 = 0; s2 < SRC; ++s2)
        c = fmaf(p_lds[t][s2], encb[s2 * TSD + d], c);
    ctx_out[((size_t)(b * TGT + tg)) * TSD + d] = c;
}

extern "C" void kernel_launch(void* const* d_in, const int* in_sizes, int n_in,
                              void* d_out, int out_size, void* d_ws, size_t ws_size,
                              hipStream_t stream) {
    const float* hid  = (const float*)d_in[0];   // (4,256,512)
    const float* enc  = (const float*)d_in[1];   // (4,256,512)
    const int*   mask = (const int*)  d_in[2];   // (4,256)
    const float* W    = (const float*)d_in[3];   // (512,1024)
    const float* bias = (const float*)d_in[4];   // (512,)
    const float* v    = (const float*)d_in[5];   // (512,)

    float* out   = (float*)d_out;
    float* ctx   = out;                       // 4*256*512
    float* probs = out + NB * TGT * TSD;      // 4*256*256

    float* hp  = (float*)d_ws;                // 1024*512 (K-scaled)
    float* epT = hp + NB * TGT * TSD;         // 4*512*256 (K-scaled, +bias, transposed)

    dim3 pb(16, 16);
    dim3 pg(TSD / 64, (NB * TGT) / 64, 2);
    proj_kernel<<<pg, pb, 0, stream>>>(hid, enc, W, bias, hp, epT);

    dim3 ag(TGT / 2, NB);
    attn_kernel<<<ag, 1024, 0, stream>>>(hp, epT, enc, mask, v, ctx, probs);
}